// Round 10
// baseline (318.753 us; speedup 1.0000x reference)
//
#include <hip/hip_runtime.h>
#include <hip/hip_bf16.h>

// ChebConv K=3 GCN — Round 10: R9 structure with the int32-overflow fix.
// R9 post-mortem: P[n] = ((b*LCAP+excl)<<10)|deg overflowed SIGNED int32
// (offset up to 4.0e6 = 22 bits; <<10 = up to 4.1e9 > 2^31). Negative packed
// word -> negative arithmetic >>10 in k_prop2 -> wild es[] reads -> crash.
// Fix: unsigned packing (22b offset | 10b deg fits exactly in u32).
// Structure (R9): prop1 fused into bucket sort (indices broadcast from LDS,
// no global es read); deg via global int atomics in lsort; basescan + norm
// array deleted (fixed per-bucket es slots, nv recomputed from packed deg);
// prop2 stages its 64-node es slice in LDS.

#define NN   100000
#define NE   3200000
#define F    16
#define CB   128                  // dst nodes per bucket
#define NBUK 782                  // ceil(NN/CB)
#define ECHK 8192                 // edges per sort chunk
#define NBLK 391                  // ceil(NE/ECHK)
#define LCAP 5120                 // per-bucket es slot (mean 4096, sigma~64)
#define HXW  1025                 // hxg row width
#define PCAP 4608                 // prop2 staged edges per 64-node block (mean 2048, s~45)

__device__ __forceinline__ float bflo(unsigned int u) {
    return __uint_as_float(u << 16);
}
__device__ __forceinline__ float bfhi(unsigned int u) {
    return __uint_as_float(u & 0xffff0000u);
}
__device__ __forceinline__ unsigned int f2bf(float f) {
    __hip_bfloat16 b = __float2bfloat16(f);
    return (unsigned int)*reinterpret_cast<unsigned short*>(&b);
}

// A1: per-chunk LDS counting sort by bucket -> chunk-major csort + run tables.
// Also accumulates global per-node degree (int atomics — R1-measured cheap).
__global__ __launch_bounds__(512) void k_lsort(const int* __restrict__ src,
        const int* __restrict__ dst, int* __restrict__ H, int* __restrict__ hxg,
        int* __restrict__ csort, int* __restrict__ deg) {
    __shared__ int pk[ECHK];        // 32KB
    __shared__ int hx[HXW];
    __shared__ int cur[1024];
    __shared__ int csum[512];
    int t = threadIdx.x, blk = blockIdx.x;
    for (int j = t; j < 1024; j += 512) hx[j] = 0;
    __syncthreads();
    int s0 = blk * ECHK;
    int lim = min(s0 + ECHK, NE);
    for (int e = s0 + t; e < lim; e += 512) {
        int d = dst[e];
        atomicAdd(&hx[d >> 7], 1);
        atomicAdd(&deg[d], 1);
    }
    __syncthreads();
    int b0 = t * 2;
    int c0 = hx[b0], c1 = hx[b0 + 1];
    if (b0 < NBUK)     H[blk * NBUK + b0]     = c0;
    if (b0 + 1 < NBUK) H[blk * NBUK + b0 + 1] = c1;
    csum[t] = c0 + c1;
    __syncthreads();
    for (int o = 1; o < 512; o <<= 1) {
        int add = (t >= o) ? csum[t - o] : 0;
        __syncthreads();
        csum[t] += add;
        __syncthreads();
    }
    int ce = csum[t] - (c0 + c1);
    hx[b0] = ce;  hx[b0 + 1] = ce + c0;
    cur[b0] = ce; cur[b0 + 1] = ce + c0;
    if (t == 511) hx[1024] = csum[511];
    __syncthreads();
    for (int j = t; j < HXW; j += 512)
        hxg[blk * HXW + j] = hx[j];
    for (int e = s0 + t; e < lim; e += 512) {
        int d = dst[e];
        int pos = atomicAdd(&cur[d >> 7], 1);
        pk[pos] = (src[e] << 7) | (d & 127);
    }
    __syncthreads();
    int len = lim - s0;
    for (int i = t; i < len; i += 512)
        csort[s0 + i] = pk[i];
}

// A2: column scan (in place): H[:,b] -> exclusive prefix over chunks.
__global__ void k_colscan(int* __restrict__ H) {
    __shared__ int tmp[512];
    int b = blockIdx.x, t = threadIdx.x;
    int v = (t < NBLK) ? H[t * NBUK + b] : 0;
    tmp[t] = v;
    __syncthreads();
    for (int o = 1; o < 512; o <<= 1) {
        int add = (t >= o) ? tmp[t - o] : 0;
        __syncthreads();
        tmp[t] += add;
        __syncthreads();
    }
    if (t < NBLK) H[t * NBUK + b] = tmp[t] - v;
}

// A3: Y0 = bf16(X0 * rsqrt(max(deg,1))); zero sentinel rows for Y0 and Y1.
__global__ __launch_bounds__(256) void k_norm(const int* __restrict__ deg,
        const float* __restrict__ X0, unsigned short* __restrict__ Y0,
        unsigned short* __restrict__ Y1) {
    int tid = blockIdx.x * 256 + threadIdx.x;
    if (tid < 4) {
        ((uint2*)Y0)[(size_t)NN * 4 + tid] = make_uint2(0u, 0u);
        ((uint2*)Y1)[(size_t)NN * 4 + tid] = make_uint2(0u, 0u);
    }
    int n = tid >> 2;
    if (n >= NN) return;
    int d = deg[n];
    float nv = rsqrtf((float)(d < 1 ? 1 : d));
    float4 x0 = ((const float4*)X0)[tid];
    uint2 o;
    o.x = f2bf(x0.x * nv) | (f2bf(x0.y * nv) << 16);
    o.y = f2bf(x0.z * nv) | (f2bf(x0.w * nv) << 16);
    ((uint2*)Y0)[tid] = o;
}

// A4: per-bucket exact dst sort (LDS) + packed CSR + coalesced es write,
// then PROP1 FUSED: gather Y0 rows with LDS-broadcast indices, write Y1.
__global__ __launch_bounds__(512) void k_sortprop1(const int* __restrict__ csort,
        const int* __restrict__ H, const int* __restrict__ hxg,
        const float* __restrict__ X0, const float* __restrict__ lm,
        int* __restrict__ es, unsigned int* __restrict__ P,
        const unsigned short* __restrict__ Y0, unsigned short* __restrict__ Y1) {
    __shared__ int pk[LCAP];        // 20KB: bucket-grouped (unsorted)
    __shared__ int pk2[LCAP];       // 20KB: dst-sorted src indices
    __shared__ int cnt[CB], loc[CB], cur[CB];
    __shared__ int lenS;
    int b = blockIdx.x, t = threadIdx.x;
    if (t < CB) cnt[t] = 0;
    if (t == 0) lenS = 0;
    __syncthreads();
    // gather this bucket's runs from all chunks (chunk-major csort);
    // NBLK < 512 so each thread owns at most one chunk.
    int mylen = 0;
    for (int c = t; c < NBLK; c += 512) {
        int h0 = hxg[c * HXW + b];
        int h1 = hxg[c * HXW + b + 1];
        int dpos = H[c * NBUK + b];            // exclusive-over-chunks placement
        int rl = h1 - h0;
        if (dpos >= LCAP) continue;
        if (dpos + rl > LCAP) rl = LCAP - dpos;
        int sbase = c * ECHK + h0;
        for (int i = 0; i < rl; ++i)
            pk[dpos + i] = csort[sbase + i];
        mylen = dpos + rl;
    }
    if (mylen > 0) atomicMax(&lenS, mylen);
    __syncthreads();
    int len = lenS;
    for (int i = t; i < len; i += 512)
        atomicAdd(&cnt[pk[i] & 127], 1);
    __syncthreads();
    if (t < CB) loc[t] = cnt[t];
    __syncthreads();
    for (int o = 1; o < CB; o <<= 1) {
        int add = 0;
        if (t < CB && t >= o) add = loc[t - o];
        __syncthreads();
        if (t < CB) loc[t] += add;
        __syncthreads();
    }
    if (t < CB) {
        int excl = loc[t] - cnt[t];
        loc[t] = excl;
        cur[t] = excl;
        int n = b * CB + t;
        if (n < NN) {
            unsigned dg = cnt[t] > 1023 ? 1023u : (unsigned)cnt[t];
            P[n] = ((unsigned)(b * LCAP + excl) << 10) | dg;   // u32: 22b off | 10b deg
        }
    }
    __syncthreads();
    for (int i = t; i < len; i += 512) {
        int p = pk[i];
        int pos = atomicAdd(&cur[p & 127], 1);
        pk2[pos] = p >> 7;                      // src index, dst-sorted
    }
    __syncthreads();
    // coalesced es writeout (fixed slot, amp ~1.0)
    for (int i = t; i < len; i += 512)
        es[b * LCAP + i] = pk2[i];
    // ---- fused prop1: 4 lanes/node, indices broadcast from LDS ----
    int nl = t >> 2, h = t & 3;
    int n = b * CB + nl;
    if (n >= NN) return;
    int beg = loc[nl];
    int lend = beg + cnt[nl];
    const uint2* Yv = (const uint2*)Y0;
    float a0 = 0.f, a1 = 0.f, a2 = 0.f, a3 = 0.f;
    for (int e0 = beg; e0 < lend; e0 += 8) {
#pragma unroll
        for (int j = 0; j < 8; ++j) {
            int sp = e0 + j;
            int s = (sp < lend) ? pk2[sp] : NN;   // LDS broadcast read
            uint2 u = Yv[(size_t)s * 4 + h];
            a0 += bflo(u.x); a1 += bfhi(u.x);
            a2 += bflo(u.y); a3 += bfhi(u.y);
        }
    }
    int dg = cnt[nl];
    float nv = rsqrtf((float)(dg < 1 ? 1 : dg));
    float r  = 2.0f / lm[0];
    float k1 = -r * nv, k2 = r - 1.0f;
    int tid4 = n * 4 + h;
    float4 x0 = ((const float4*)X0)[tid4];
    float x1a = k1 * a0 + k2 * x0.x;
    float x1b = k1 * a1 + k2 * x0.y;
    float x1c = k1 * a2 + k2 * x0.z;
    float x1d = k1 * a3 + k2 * x0.w;
    uint2 o;
    o.x = f2bf(nv * x1a) | (f2bf(nv * x1b) << 16);
    o.y = f2bf(nv * x1c) | (f2bf(nv * x1d) << 16);
    ((uint2*)Y1)[tid4] = o;
}

// A5: prop2 + epilogue. Block = 64 nodes; es slice staged in LDS (coalesced),
// indices broadcast from LDS; x2 + [x0|x1|x2]@W^T + relu.
__global__ __launch_bounds__(256) void k_prop2(const unsigned int* __restrict__ P,
        const int* __restrict__ es, const unsigned short* __restrict__ Y1,
        const float* __restrict__ X0, const float* __restrict__ lm,
        const float* __restrict__ W, float* __restrict__ out) {
    __shared__ int sidx[PCAP];      // 18KB
    __shared__ float Ws[96];
    int blk = blockIdx.x, t = threadIdx.x;
    int b = blk >> 1, half = blk & 1;
    int n0 = b * CB + half * 64;
    if (n0 >= NN) return;           // uniform per block
    if (t < 96) Ws[t] = W[t];
    unsigned pk0 = P[n0];
    int nL = min(n0 + 63, NN - 1);
    unsigned pkL = P[nL];
    int st = (int)(pk0 >> 10);
    int en = (int)(pkL >> 10) + (int)(pkL & 1023u);
    int slen = en - st;
    if (slen > PCAP) slen = PCAP;   // unreachable for this input (>50 sigma)
    for (int i = t; i < slen; i += 256)
        sidx[i] = es[st + i];
    __syncthreads();
    int n = n0 + (t >> 2), h = t & 3;
    if (n >= NN) return;
    unsigned pkn = P[n];
    int beg = (int)(pkn >> 10) - st;
    int dg = (int)(pkn & 1023u);
    int lend = min(beg + dg, slen);
    const uint2* Yv = (const uint2*)Y1;
    float a0 = 0.f, a1 = 0.f, a2 = 0.f, a3 = 0.f;
    for (int e0 = beg; e0 < lend; e0 += 8) {
#pragma unroll
        for (int j = 0; j < 8; ++j) {
            int sp = e0 + j;
            int s = (sp < lend) ? sidx[sp] : NN;
            uint2 u = Yv[(size_t)s * 4 + h];
            a0 += bflo(u.x); a1 += bfhi(u.x);
            a2 += bflo(u.y); a3 += bfhi(u.y);
        }
    }
    float nv = rsqrtf((float)(dg < 1 ? 1 : dg));
    float rn = 1.0f / nv;
    float r  = 2.0f / lm[0];
    int tid4 = n * 4 + h;
    float4 x0 = ((const float4*)X0)[tid4];
    uint2 uy = ((const uint2*)Y1)[tid4];
    float x1a = bflo(uy.x) * rn, x1b = bfhi(uy.x) * rn;
    float x1c = bflo(uy.y) * rn, x1d = bfhi(uy.y) * rn;
    float c1 = -2.0f * r * nv, c2 = 2.0f * (r - 1.0f);
    float x2a = c1 * a0 + c2 * x1a - x0.x;
    float x2b = c1 * a1 + c2 * x1b - x0.y;
    float x2c = c1 * a2 + c2 * x1c - x0.z;
    float x2d = c1 * a3 + c2 * x1d - x0.w;
    int f0 = 4 * h;
    float t0 = Ws[f0] * x0.x + Ws[f0 + 1] * x0.y + Ws[f0 + 2] * x0.z + Ws[f0 + 3] * x0.w
             + Ws[16 + f0] * x1a + Ws[17 + f0] * x1b + Ws[18 + f0] * x1c + Ws[19 + f0] * x1d
             + Ws[32 + f0] * x2a + Ws[33 + f0] * x2b + Ws[34 + f0] * x2c + Ws[35 + f0] * x2d;
    float t1 = Ws[48 + f0] * x0.x + Ws[49 + f0] * x0.y + Ws[50 + f0] * x0.z + Ws[51 + f0] * x0.w
             + Ws[64 + f0] * x1a + Ws[65 + f0] * x1b + Ws[66 + f0] * x1c + Ws[67 + f0] * x1d
             + Ws[80 + f0] * x2a + Ws[81 + f0] * x2b + Ws[82 + f0] * x2c + Ws[83 + f0] * x2d;
    t0 += __shfl_xor(t0, 2, 4); t0 += __shfl_xor(t0, 1, 4);
    t1 += __shfl_xor(t1, 2, 4); t1 += __shfl_xor(t1, 1, 4);
    if (h == 0) {
        out[(size_t)n * 2 + 0] = fmaxf(t0, 0.f);
        out[(size_t)n * 2 + 1] = fmaxf(t1, 0.f);
    }
}

extern "C" void kernel_launch(void* const* d_in, const int* in_sizes, int n_in,
                              void* d_out, int out_size, void* d_ws, size_t ws_size,
                              hipStream_t stream) {
    const float* X0  = (const float*)d_in[0];
    const float* W   = (const float*)d_in[1];
    const int*   src = (const int*)d_in[2];
    const int*   dst = (const int*)d_in[3];
    const float* lm  = (const float*)d_in[4];
    float* out = (float*)d_out;

    // Workspace (~39 MB of 256MiB):
    // H[NBLK*NBUK] | hxg[NBLK*HXW] | csort[NE] | es[NBUK*LCAP] | P[NN]
    // | deg[NN] | Y0[(NN+1)*F bf16] | Y1[(NN+1)*F bf16]
    int*   H     = (int*)d_ws;
    int*   hxg   = H + (size_t)NBLK * NBUK;
    int*   csort = hxg + (size_t)NBLK * HXW;
    int*   es    = csort + NE;
    unsigned int* P = (unsigned int*)(es + (size_t)NBUK * LCAP);
    int*   deg   = (int*)(P + NN);
    unsigned short* Y0 = (unsigned short*)(deg + NN);
    unsigned short* Y1 = Y0 + (size_t)(NN + 1) * F;

    hipMemsetAsync(deg, 0, NN * sizeof(int), stream);
    k_lsort    <<<NBLK, 512, 0, stream>>>(src, dst, H, hxg, csort, deg);
    k_colscan  <<<NBUK, 512, 0, stream>>>(H);
    k_norm     <<<(NN * 4 + 255) / 256, 256, 0, stream>>>(deg, X0, Y0, Y1);
    k_sortprop1<<<NBUK, 512, 0, stream>>>(csort, H, hxg, X0, lm, es, P, Y0, Y1);
    k_prop2    <<<NBUK * 2, 256, 0, stream>>>(P, es, Y1, X0, lm, W, out);
}

// Round 11
// 187.052 us; speedup vs baseline: 1.7041x; 1.7041x over previous
//
#include <hip/hip_runtime.h>
#include <hip/hip_bf16.h>

// ChebConv K=3 GCN — Round 11: R8 pipeline + packed CSR + LDS-staged prop indices.
// R10 post-mortem: adding atomicAdd(&deg[d],1) to k_lsort exploded WRITE
// 16->115MB (3.2M cross-XCD atomics to a 400KB array = line thrash between
// non-coherent L2s; ~36B writeback per atomic) and lsort 33->148us. Global
// atomics to small hot arrays are NOT cheap. Revert to deg-from-cnt inside
// k_sort (R8-proven). Keep from R10: packed u32 CSR (22b off | 10b deg, fixed
// per-bucket es slots, basescan deleted) and LDS-staged broadcast indices,
// now used in BOTH props (kills shfl chain + per-lane global es reads).

#define NN   100000
#define NE   3200000
#define F    16
#define CB   128                  // dst nodes per bucket
#define NBUK 782                  // ceil(NN/CB)
#define ECHK 8192                 // edges per sort chunk
#define NBLK 391                  // ceil(NE/ECHK)
#define LCAP 5120                 // per-bucket es slot (mean 4096, sigma~64)
#define HXW  1025                 // hxg row width
#define PCAP 4608                 // staged edges per 64-node prop block (mean 2048, s~45)

__device__ __forceinline__ float bflo(unsigned int u) {
    return __uint_as_float(u << 16);
}
__device__ __forceinline__ float bfhi(unsigned int u) {
    return __uint_as_float(u & 0xffff0000u);
}
__device__ __forceinline__ unsigned int f2bf(float f) {
    __hip_bfloat16 b = __float2bfloat16(f);
    return (unsigned int)*reinterpret_cast<unsigned short*>(&b);
}

// A1: per-chunk LDS counting sort by bucket -> chunk-major csort + run tables.
// (R8 version — no global deg atomics.)
__global__ __launch_bounds__(512) void k_lsort(const int* __restrict__ src,
        const int* __restrict__ dst, int* __restrict__ H, int* __restrict__ hxg,
        int* __restrict__ csort) {
    __shared__ int pk[ECHK];        // 32KB
    __shared__ int hx[HXW];
    __shared__ int cur[1024];
    __shared__ int csum[512];
    int t = threadIdx.x, blk = blockIdx.x;
    for (int j = t; j < 1024; j += 512) hx[j] = 0;
    __syncthreads();
    int s0 = blk * ECHK;
    int lim = min(s0 + ECHK, NE);
    for (int e = s0 + t; e < lim; e += 512)
        atomicAdd(&hx[dst[e] >> 7], 1);
    __syncthreads();
    int b0 = t * 2;
    int c0 = hx[b0], c1 = hx[b0 + 1];
    if (b0 < NBUK)     H[blk * NBUK + b0]     = c0;
    if (b0 + 1 < NBUK) H[blk * NBUK + b0 + 1] = c1;
    csum[t] = c0 + c1;
    __syncthreads();
    for (int o = 1; o < 512; o <<= 1) {
        int add = (t >= o) ? csum[t - o] : 0;
        __syncthreads();
        csum[t] += add;
        __syncthreads();
    }
    int ce = csum[t] - (c0 + c1);
    hx[b0] = ce;  hx[b0 + 1] = ce + c0;
    cur[b0] = ce; cur[b0 + 1] = ce + c0;
    if (t == 511) hx[1024] = csum[511];
    __syncthreads();
    for (int j = t; j < HXW; j += 512)
        hxg[blk * HXW + j] = hx[j];
    for (int e = s0 + t; e < lim; e += 512) {
        int d = dst[e];
        int pos = atomicAdd(&cur[d >> 7], 1);
        pk[pos] = (src[e] << 7) | (d & 127);
    }
    __syncthreads();
    int len = lim - s0;
    for (int i = t; i < len; i += 512)
        csort[s0 + i] = pk[i];
}

// A2: column scan (in place): H[:,b] -> exclusive prefix over chunks.
__global__ void k_colscan(int* __restrict__ H) {
    __shared__ int tmp[512];
    int b = blockIdx.x, t = threadIdx.x;
    int v = (t < NBLK) ? H[t * NBUK + b] : 0;
    tmp[t] = v;
    __syncthreads();
    for (int o = 1; o < 512; o <<= 1) {
        int add = (t >= o) ? tmp[t - o] : 0;
        __syncthreads();
        tmp[t] += add;
        __syncthreads();
    }
    if (t < NBLK) H[t * NBUK + b] = tmp[t] - v;
}

// A3: per-bucket exact dst sort (LDS) + packed CSR + coalesced es write
// + norm from cnt + Y0 = bf16(X0*nv) (+ zero sentinel rows for Y0/Y1).
__global__ __launch_bounds__(512) void k_sort(const int* __restrict__ csort,
        const int* __restrict__ H, const int* __restrict__ hxg,
        const float* __restrict__ X0, int* __restrict__ es,
        unsigned int* __restrict__ P, unsigned short* __restrict__ Y0,
        unsigned short* __restrict__ Y1) {
    __shared__ int pk[LCAP];        // 20KB: bucket-grouped (unsorted)
    __shared__ int pk2[LCAP];       // 20KB: dst-sorted src indices
    __shared__ int cnt[CB], loc[CB], cur[CB];
    __shared__ float nvs[CB];
    __shared__ int lenS;
    int b = blockIdx.x, t = threadIdx.x;
    if (t < CB) cnt[t] = 0;
    if (t == 0) lenS = 0;
    if (b == 0 && t < 8) {          // zero sentinel rows (uint2 = 4 per row)
        ((uint2*)Y0)[(size_t)NN * 4 + (t & 3)] = make_uint2(0u, 0u);
        ((uint2*)Y1)[(size_t)NN * 4 + (t & 3)] = make_uint2(0u, 0u);
    }
    __syncthreads();
    // gather this bucket's runs from all chunks (chunk-major csort);
    // NBLK=391 < 512 so each thread owns at most one chunk.
    int mylen = 0;
    for (int c = t; c < NBLK; c += 512) {
        int h0 = hxg[c * HXW + b];
        int h1 = hxg[c * HXW + b + 1];
        int dpos = H[c * NBUK + b];            // exclusive-over-chunks placement
        int rl = h1 - h0;
        if (dpos >= LCAP) continue;
        if (dpos + rl > LCAP) rl = LCAP - dpos;
        int sbase = c * ECHK + h0;
        for (int i = 0; i < rl; ++i)
            pk[dpos + i] = csort[sbase + i];
        mylen = dpos + rl;
    }
    if (mylen > 0) atomicMax(&lenS, mylen);
    __syncthreads();
    int len = lenS;
    for (int i = t; i < len; i += 512)
        atomicAdd(&cnt[pk[i] & 127], 1);
    __syncthreads();
    if (t < CB) loc[t] = cnt[t];
    __syncthreads();
    for (int o = 1; o < CB; o <<= 1) {
        int add = 0;
        if (t < CB && t >= o) add = loc[t - o];
        __syncthreads();
        if (t < CB) loc[t] += add;
        __syncthreads();
    }
    if (t < CB) {
        int excl = loc[t] - cnt[t];
        loc[t] = excl;
        cur[t] = excl;
        int n = b * CB + t;
        if (n < NN) {
            unsigned dg = cnt[t] > 1023 ? 1023u : (unsigned)cnt[t];
            P[n] = ((unsigned)(b * LCAP + excl) << 10) | dg;   // u32: 22b off | 10b deg
            nvs[t] = rsqrtf((float)(cnt[t] < 1 ? 1 : cnt[t]));
        }
    }
    __syncthreads();
    // Y0 for this bucket's nodes (coalesced: 2048 uint2)
    for (int j = t; j < CB * 4; j += 512) {
        int dl = j >> 2;
        int n = b * CB + dl;
        if (n < NN) {
            float nv = nvs[dl];
            size_t g4 = (size_t)n * 4 + (j & 3);
            float4 x0 = ((const float4*)X0)[g4];
            uint2 o;
            o.x = f2bf(x0.x * nv) | (f2bf(x0.y * nv) << 16);
            o.y = f2bf(x0.z * nv) | (f2bf(x0.w * nv) << 16);
            ((uint2*)Y0)[g4] = o;
        }
    }
    // dst-sort scatter (LDS int atomics)
    for (int i = t; i < len; i += 512) {
        int p = pk[i];
        int pos = atomicAdd(&cur[p & 127], 1);
        pk2[pos] = p >> 7;                      // src index, dst-sorted
    }
    __syncthreads();
    // coalesced es writeout (fixed slot, amp ~1.0)
    for (int i = t; i < len; i += 512)
        es[b * LCAP + i] = pk2[i];
}

// A4: prop1. Block = 64 nodes; es slice staged in LDS (coalesced in,
// broadcast ds_read out); 4 lanes/node uint2 gathers; writes Y1 = bf16(nv*x1).
__global__ __launch_bounds__(256) void k_prop1(const unsigned int* __restrict__ P,
        const int* __restrict__ es, const unsigned short* __restrict__ Y0,
        const float* __restrict__ X0, const float* __restrict__ lm,
        unsigned short* __restrict__ Y1) {
    __shared__ int sidx[PCAP];      // 18KB
    int blk = blockIdx.x, t = threadIdx.x;
    int b = blk >> 1, half = blk & 1;
    int n0 = b * CB + half * 64;
    if (n0 >= NN) return;           // uniform per block
    unsigned pk0 = P[n0];
    int nL = min(n0 + 63, NN - 1);
    unsigned pkL = P[nL];
    int st = (int)(pk0 >> 10);
    int en = (int)(pkL >> 10) + (int)(pkL & 1023u);
    int slen = en - st;
    if (slen > PCAP) slen = PCAP;   // unreachable for this input (>50 sigma)
    for (int i = t; i < slen; i += 256)
        sidx[i] = es[st + i];
    __syncthreads();
    int n = n0 + (t >> 2), h = t & 3;
    if (n >= NN) return;
    unsigned pkn = P[n];
    int beg = (int)(pkn >> 10) - st;
    int dg = (int)(pkn & 1023u);
    int lend = min(beg + dg, slen);
    const uint2* Yv = (const uint2*)Y0;
    float a0 = 0.f, a1 = 0.f, a2 = 0.f, a3 = 0.f;
    for (int e0 = beg; e0 < lend; e0 += 8) {
#pragma unroll
        for (int j = 0; j < 8; ++j) {
            int sp = e0 + j;
            int s = (sp < lend) ? sidx[sp] : NN;   // LDS broadcast read
            uint2 u = Yv[(size_t)s * 4 + h];
            a0 += bflo(u.x); a1 += bfhi(u.x);
            a2 += bflo(u.y); a3 += bfhi(u.y);
        }
    }
    float nv = rsqrtf((float)(dg < 1 ? 1 : dg));
    float r  = 2.0f / lm[0];
    float k1 = -r * nv, k2 = r - 1.0f;
    int tid4 = n * 4 + h;
    float4 x0 = ((const float4*)X0)[tid4];
    float x1a = k1 * a0 + k2 * x0.x;
    float x1b = k1 * a1 + k2 * x0.y;
    float x1c = k1 * a2 + k2 * x0.z;
    float x1d = k1 * a3 + k2 * x0.w;
    uint2 o;
    o.x = f2bf(nv * x1a) | (f2bf(nv * x1b) << 16);
    o.y = f2bf(nv * x1c) | (f2bf(nv * x1d) << 16);
    ((uint2*)Y1)[tid4] = o;
}

// A5: prop2 + epilogue: x2 + [x0|x1|x2]@W^T + relu. Same staging as prop1.
__global__ __launch_bounds__(256) void k_prop2(const unsigned int* __restrict__ P,
        const int* __restrict__ es, const unsigned short* __restrict__ Y1,
        const float* __restrict__ X0, const float* __restrict__ lm,
        const float* __restrict__ W, float* __restrict__ out) {
    __shared__ int sidx[PCAP];      // 18KB
    __shared__ float Ws[96];
    int blk = blockIdx.x, t = threadIdx.x;
    int b = blk >> 1, half = blk & 1;
    int n0 = b * CB + half * 64;
    if (n0 >= NN) return;           // uniform per block
    if (t < 96) Ws[t] = W[t];
    unsigned pk0 = P[n0];
    int nL = min(n0 + 63, NN - 1);
    unsigned pkL = P[nL];
    int st = (int)(pk0 >> 10);
    int en = (int)(pkL >> 10) + (int)(pkL & 1023u);
    int slen = en - st;
    if (slen > PCAP) slen = PCAP;
    for (int i = t; i < slen; i += 256)
        sidx[i] = es[st + i];
    __syncthreads();
    int n = n0 + (t >> 2), h = t & 3;
    if (n >= NN) return;
    unsigned pkn = P[n];
    int beg = (int)(pkn >> 10) - st;
    int dg = (int)(pkn & 1023u);
    int lend = min(beg + dg, slen);
    const uint2* Yv = (const uint2*)Y1;
    float a0 = 0.f, a1 = 0.f, a2 = 0.f, a3 = 0.f;
    for (int e0 = beg; e0 < lend; e0 += 8) {
#pragma unroll
        for (int j = 0; j < 8; ++j) {
            int sp = e0 + j;
            int s = (sp < lend) ? sidx[sp] : NN;
            uint2 u = Yv[(size_t)s * 4 + h];
            a0 += bflo(u.x); a1 += bfhi(u.x);
            a2 += bflo(u.y); a3 += bfhi(u.y);
        }
    }
    float nv = rsqrtf((float)(dg < 1 ? 1 : dg));
    float rn = 1.0f / nv;
    float r  = 2.0f / lm[0];
    int tid4 = n * 4 + h;
    float4 x0 = ((const float4*)X0)[tid4];
    uint2 uy = ((const uint2*)Y1)[tid4];
    float x1a = bflo(uy.x) * rn, x1b = bfhi(uy.x) * rn;
    float x1c = bflo(uy.y) * rn, x1d = bfhi(uy.y) * rn;
    float c1 = -2.0f * r * nv, c2 = 2.0f * (r - 1.0f);
    float x2a = c1 * a0 + c2 * x1a - x0.x;
    float x2b = c1 * a1 + c2 * x1b - x0.y;
    float x2c = c1 * a2 + c2 * x1c - x0.z;
    float x2d = c1 * a3 + c2 * x1d - x0.w;
    int f0 = 4 * h;
    float t0 = Ws[f0] * x0.x + Ws[f0 + 1] * x0.y + Ws[f0 + 2] * x0.z + Ws[f0 + 3] * x0.w
             + Ws[16 + f0] * x1a + Ws[17 + f0] * x1b + Ws[18 + f0] * x1c + Ws[19 + f0] * x1d
             + Ws[32 + f0] * x2a + Ws[33 + f0] * x2b + Ws[34 + f0] * x2c + Ws[35 + f0] * x2d;
    float t1 = Ws[48 + f0] * x0.x + Ws[49 + f0] * x0.y + Ws[50 + f0] * x0.z + Ws[51 + f0] * x0.w
             + Ws[64 + f0] * x1a + Ws[65 + f0] * x1b + Ws[66 + f0] * x1c + Ws[67 + f0] * x1d
             + Ws[80 + f0] * x2a + Ws[81 + f0] * x2b + Ws[82 + f0] * x2c + Ws[83 + f0] * x2d;
    t0 += __shfl_xor(t0, 2, 4); t0 += __shfl_xor(t0, 1, 4);
    t1 += __shfl_xor(t1, 2, 4); t1 += __shfl_xor(t1, 1, 4);
    if (h == 0) {
        out[(size_t)n * 2 + 0] = fmaxf(t0, 0.f);
        out[(size_t)n * 2 + 1] = fmaxf(t1, 0.f);
    }
}

extern "C" void kernel_launch(void* const* d_in, const int* in_sizes, int n_in,
                              void* d_out, int out_size, void* d_ws, size_t ws_size,
                              hipStream_t stream) {
    const float* X0  = (const float*)d_in[0];
    const float* W   = (const float*)d_in[1];
    const int*   src = (const int*)d_in[2];
    const int*   dst = (const int*)d_in[3];
    const float* lm  = (const float*)d_in[4];
    float* out = (float*)d_out;

    // Workspace (~38 MB of 256MiB):
    // H[NBLK*NBUK] | hxg[NBLK*HXW] | csort[NE] | es[NBUK*LCAP] | P[NN]
    // | Y0[(NN+1)*F bf16] | Y1[(NN+1)*F bf16]
    int*   H     = (int*)d_ws;
    int*   hxg   = H + (size_t)NBLK * NBUK;
    int*   csort = hxg + (size_t)NBLK * HXW;
    int*   es    = csort + NE;
    unsigned int* P = (unsigned int*)(es + (size_t)NBUK * LCAP);
    unsigned short* Y0 = (unsigned short*)(P + NN);
    unsigned short* Y1 = Y0 + (size_t)(NN + 1) * F;

    k_lsort  <<<NBLK, 512, 0, stream>>>(src, dst, H, hxg, csort);
    k_colscan<<<NBUK, 512, 0, stream>>>(H);
    k_sort   <<<NBUK, 512, 0, stream>>>(csort, H, hxg, X0, es, P, Y0, Y1);
    k_prop1  <<<NBUK * 2, 256, 0, stream>>>(P, es, Y0, X0, lm, Y1);
    k_prop2  <<<NBUK * 2, 256, 0, stream>>>(P, es, Y1, X0, lm, W, out);
}

// Round 12
// 175.125 us; speedup vs baseline: 1.8201x; 1.0681x over previous
//
#include <hip/hip_runtime.h>
#include <hip/hip_bf16.h>

// ChebConv K=3 GCN — Round 12: colscan + H deleted (hxg-derived counts, in-block scan).
// R11 post-mortem: 187us best; no kernel >44us (top-5 all harness fills).
// Remaining levers are pass deletion: H[c][b] == hxg[c][b+1]-hxg[c][b], so
// k_sort loads one adjacent pair per chunk, scans the 391 counts in LDS
// (9 H-S steps) for run placement, and takes bucket length from the scan
// total (atomicMax hack dies). Pipeline: lsort -> sort -> prop1 -> prop2 (4
// dispatches = structural floor without cooperative launch).

#define NN   100000
#define NE   3200000
#define F    16
#define CB   128                  // dst nodes per bucket
#define NBUK 782                  // ceil(NN/CB)
#define ECHK 8192                 // edges per sort chunk
#define NBLK 391                  // ceil(NE/ECHK)
#define LCAP 5120                 // per-bucket es slot (mean 4096, sigma~64)
#define HXW  1025                 // hxg row width (1024 run starts + total)
#define PCAP 4608                 // staged edges per 64-node prop block (mean 2048, s~45)

__device__ __forceinline__ float bflo(unsigned int u) {
    return __uint_as_float(u << 16);
}
__device__ __forceinline__ float bfhi(unsigned int u) {
    return __uint_as_float(u & 0xffff0000u);
}
__device__ __forceinline__ unsigned int f2bf(float f) {
    __hip_bfloat16 b = __float2bfloat16(f);
    return (unsigned int)*reinterpret_cast<unsigned short*>(&b);
}

// A1: per-chunk LDS counting sort by bucket -> chunk-major csort + run table hxg.
__global__ __launch_bounds__(512) void k_lsort(const int* __restrict__ src,
        const int* __restrict__ dst, int* __restrict__ hxg, int* __restrict__ csort) {
    __shared__ int pk[ECHK];        // 32KB
    __shared__ int hx[HXW];
    __shared__ int cur[1024];
    __shared__ int csum[512];
    int t = threadIdx.x, blk = blockIdx.x;
    for (int j = t; j < 1024; j += 512) hx[j] = 0;
    __syncthreads();
    int s0 = blk * ECHK;
    int lim = min(s0 + ECHK, NE);
    for (int e = s0 + t; e < lim; e += 512)
        atomicAdd(&hx[dst[e] >> 7], 1);
    __syncthreads();
    int b0 = t * 2;
    int c0 = hx[b0], c1 = hx[b0 + 1];
    csum[t] = c0 + c1;
    __syncthreads();
    for (int o = 1; o < 512; o <<= 1) {
        int add = (t >= o) ? csum[t - o] : 0;
        __syncthreads();
        csum[t] += add;
        __syncthreads();
    }
    int ce = csum[t] - (c0 + c1);
    hx[b0] = ce;  hx[b0 + 1] = ce + c0;
    cur[b0] = ce; cur[b0 + 1] = ce + c0;
    if (t == 511) hx[1024] = csum[511];
    __syncthreads();
    for (int j = t; j < HXW; j += 512)
        hxg[blk * HXW + j] = hx[j];
    for (int e = s0 + t; e < lim; e += 512) {
        int d = dst[e];
        int pos = atomicAdd(&cur[d >> 7], 1);
        pk[pos] = (src[e] << 7) | (d & 127);
    }
    __syncthreads();
    int len = lim - s0;
    for (int i = t; i < len; i += 512)
        csort[s0 + i] = pk[i];
}

// A2: per-bucket exact dst sort. Run bounds from hxg (adjacent pair per chunk);
// run placement via in-block 391-entry scan; then exact counting sort by dst,
// packed CSR, norm from cnt, Y0 = bf16(X0*nv), coalesced es write.
__global__ __launch_bounds__(512) void k_sort(const int* __restrict__ csort,
        const int* __restrict__ hxg, const float* __restrict__ X0,
        int* __restrict__ es, unsigned int* __restrict__ P,
        unsigned short* __restrict__ Y0, unsigned short* __restrict__ Y1) {
    __shared__ int pk[LCAP];        // 20KB: bucket-grouped (unsorted)
    __shared__ int pk2[LCAP];       // 20KB: dst-sorted src indices
    __shared__ int dsc[512];        // per-chunk count -> inclusive scan
    __shared__ int cnt[CB], loc[CB], cur[CB];
    __shared__ float nvs[CB];
    int b = blockIdx.x, t = threadIdx.x;
    int h0 = 0, c = 0;
    if (t < NBLK) {
        h0 = hxg[t * HXW + b];              // adjacent pair: one 8B region
        c  = hxg[t * HXW + b + 1] - h0;
    }
    dsc[t] = c;
    if (t < CB) cnt[t] = 0;
    if (b == 0 && t < 4) {                  // zero sentinel rows
        ((uint2*)Y0)[(size_t)NN * 4 + t] = make_uint2(0u, 0u);
        ((uint2*)Y1)[(size_t)NN * 4 + t] = make_uint2(0u, 0u);
    }
    __syncthreads();
    for (int o = 1; o < 512; o <<= 1) {     // H-S inclusive scan of chunk counts
        int add = (t >= o) ? dsc[t - o] : 0;
        __syncthreads();
        dsc[t] += add;
        __syncthreads();
    }
    int len = dsc[511];                     // bucket total
    int dpos = dsc[t] - c;                  // my run's placement (exclusive)
    if (len > LCAP) len = LCAP;             // statistically unreachable
    // gather my chunk's run from chunk-major csort
    if (c > 0 && dpos < LCAP) {
        int rl = c;
        if (dpos + rl > LCAP) rl = LCAP - dpos;
        int sbase = t * ECHK + h0;
        for (int i = 0; i < rl; ++i)
            pk[dpos + i] = csort[sbase + i];
    }
    __syncthreads();
    for (int i = t; i < len; i += 512)
        atomicAdd(&cnt[pk[i] & 127], 1);
    __syncthreads();
    if (t < CB) loc[t] = cnt[t];
    __syncthreads();
    for (int o = 1; o < CB; o <<= 1) {
        int add = 0;
        if (t < CB && t >= o) add = loc[t - o];
        __syncthreads();
        if (t < CB) loc[t] += add;
        __syncthreads();
    }
    if (t < CB) {
        int excl = loc[t] - cnt[t];
        loc[t] = excl;
        cur[t] = excl;
        int n = b * CB + t;
        if (n < NN) {
            unsigned dg = cnt[t] > 1023 ? 1023u : (unsigned)cnt[t];
            P[n] = ((unsigned)(b * LCAP + excl) << 10) | dg;   // u32: 22b off | 10b deg
            nvs[t] = rsqrtf((float)(cnt[t] < 1 ? 1 : cnt[t]));
        }
    }
    __syncthreads();
    // Y0 for this bucket's nodes (coalesced: 512 uint2 per round)
    for (int j = t; j < CB * 4; j += 512) {
        int dl = j >> 2;
        int n = b * CB + dl;
        if (n < NN) {
            float nv = nvs[dl];
            size_t g4 = (size_t)n * 4 + (j & 3);
            float4 x0 = ((const float4*)X0)[g4];
            uint2 o;
            o.x = f2bf(x0.x * nv) | (f2bf(x0.y * nv) << 16);
            o.y = f2bf(x0.z * nv) | (f2bf(x0.w * nv) << 16);
            ((uint2*)Y0)[g4] = o;
        }
    }
    // dst-sort scatter (LDS int atomics)
    for (int i = t; i < len; i += 512) {
        int p = pk[i];
        int pos = atomicAdd(&cur[p & 127], 1);
        pk2[pos] = p >> 7;                  // src index, dst-sorted
    }
    __syncthreads();
    // coalesced es writeout (fixed per-bucket slot, amp ~1.0)
    for (int i = t; i < len; i += 512)
        es[b * LCAP + i] = pk2[i];
}

// A3: prop1. Block = 64 nodes; es slice staged in LDS (coalesced in,
// broadcast ds_read out); 4 lanes/node uint2 gathers; writes Y1 = bf16(nv*x1).
__global__ __launch_bounds__(256) void k_prop1(const unsigned int* __restrict__ P,
        const int* __restrict__ es, const unsigned short* __restrict__ Y0,
        const float* __restrict__ X0, const float* __restrict__ lm,
        unsigned short* __restrict__ Y1) {
    __shared__ int sidx[PCAP];      // 18KB
    int blk = blockIdx.x, t = threadIdx.x;
    int b = blk >> 1, half = blk & 1;
    int n0 = b * CB + half * 64;
    if (n0 >= NN) return;           // uniform per block
    unsigned pk0 = P[n0];
    int nL = min(n0 + 63, NN - 1);
    unsigned pkL = P[nL];
    int st = (int)(pk0 >> 10);
    int en = (int)(pkL >> 10) + (int)(pkL & 1023u);
    int slen = en - st;
    if (slen > PCAP) slen = PCAP;   // unreachable for this input (>50 sigma)
    for (int i = t; i < slen; i += 256)
        sidx[i] = es[st + i];
    __syncthreads();
    int n = n0 + (t >> 2), h = t & 3;
    if (n >= NN) return;
    unsigned pkn = P[n];
    int beg = (int)(pkn >> 10) - st;
    int dg = (int)(pkn & 1023u);
    int lend = min(beg + dg, slen);
    const uint2* Yv = (const uint2*)Y0;
    float a0 = 0.f, a1 = 0.f, a2 = 0.f, a3 = 0.f;
    for (int e0 = beg; e0 < lend; e0 += 8) {
#pragma unroll
        for (int j = 0; j < 8; ++j) {
            int sp = e0 + j;
            int s = (sp < lend) ? sidx[sp] : NN;   // LDS broadcast read
            uint2 u = Yv[(size_t)s * 4 + h];
            a0 += bflo(u.x); a1 += bfhi(u.x);
            a2 += bflo(u.y); a3 += bfhi(u.y);
        }
    }
    float nv = rsqrtf((float)(dg < 1 ? 1 : dg));
    float r  = 2.0f / lm[0];
    float k1 = -r * nv, k2 = r - 1.0f;
    int tid4 = n * 4 + h;
    float4 x0 = ((const float4*)X0)[tid4];
    float x1a = k1 * a0 + k2 * x0.x;
    float x1b = k1 * a1 + k2 * x0.y;
    float x1c = k1 * a2 + k2 * x0.z;
    float x1d = k1 * a3 + k2 * x0.w;
    uint2 o;
    o.x = f2bf(nv * x1a) | (f2bf(nv * x1b) << 16);
    o.y = f2bf(nv * x1c) | (f2bf(nv * x1d) << 16);
    ((uint2*)Y1)[tid4] = o;
}

// A4: prop2 + epilogue: x2 + [x0|x1|x2]@W^T + relu. Same staging as prop1.
// x1 reconstruction uses rn = sqrt(deg) (no rcp chain).
__global__ __launch_bounds__(256) void k_prop2(const unsigned int* __restrict__ P,
        const int* __restrict__ es, const unsigned short* __restrict__ Y1,
        const float* __restrict__ X0, const float* __restrict__ lm,
        const float* __restrict__ W, float* __restrict__ out) {
    __shared__ int sidx[PCAP];      // 18KB
    __shared__ float Ws[96];
    int blk = blockIdx.x, t = threadIdx.x;
    int b = blk >> 1, half = blk & 1;
    int n0 = b * CB + half * 64;
    if (n0 >= NN) return;           // uniform per block
    if (t < 96) Ws[t] = W[t];
    unsigned pk0 = P[n0];
    int nL = min(n0 + 63, NN - 1);
    unsigned pkL = P[nL];
    int st = (int)(pk0 >> 10);
    int en = (int)(pkL >> 10) + (int)(pkL & 1023u);
    int slen = en - st;
    if (slen > PCAP) slen = PCAP;
    for (int i = t; i < slen; i += 256)
        sidx[i] = es[st + i];
    __syncthreads();
    int n = n0 + (t >> 2), h = t & 3;
    if (n >= NN) return;
    unsigned pkn = P[n];
    int beg = (int)(pkn >> 10) - st;
    int dg = (int)(pkn & 1023u);
    int lend = min(beg + dg, slen);
    const uint2* Yv = (const uint2*)Y1;
    float a0 = 0.f, a1 = 0.f, a2 = 0.f, a3 = 0.f;
    for (int e0 = beg; e0 < lend; e0 += 8) {
#pragma unroll
        for (int j = 0; j < 8; ++j) {
            int sp = e0 + j;
            int s = (sp < lend) ? sidx[sp] : NN;
            uint2 u = Yv[(size_t)s * 4 + h];
            a0 += bflo(u.x); a1 += bfhi(u.x);
            a2 += bflo(u.y); a3 += bfhi(u.y);
        }
    }
    int dc = dg < 1 ? 1 : dg;
    float nv = rsqrtf((float)dc);
    float rn = sqrtf((float)dc);    // 1/nv without rcp
    float r  = 2.0f / lm[0];
    int tid4 = n * 4 + h;
    float4 x0 = ((const float4*)X0)[tid4];
    uint2 uy = ((const uint2*)Y1)[tid4];
    float x1a = bflo(uy.x) * rn, x1b = bfhi(uy.x) * rn;
    float x1c = bflo(uy.y) * rn, x1d = bfhi(uy.y) * rn;
    float c1 = -2.0f * r * nv, c2 = 2.0f * (r - 1.0f);
    float x2a = c1 * a0 + c2 * x1a - x0.x;
    float x2b = c1 * a1 + c2 * x1b - x0.y;
    float x2c = c1 * a2 + c2 * x1c - x0.z;
    float x2d = c1 * a3 + c2 * x1d - x0.w;
    int f0 = 4 * h;
    float t0 = Ws[f0] * x0.x + Ws[f0 + 1] * x0.y + Ws[f0 + 2] * x0.z + Ws[f0 + 3] * x0.w
             + Ws[16 + f0] * x1a + Ws[17 + f0] * x1b + Ws[18 + f0] * x1c + Ws[19 + f0] * x1d
             + Ws[32 + f0] * x2a + Ws[33 + f0] * x2b + Ws[34 + f0] * x2c + Ws[35 + f0] * x2d;
    float t1 = Ws[48 + f0] * x0.x + Ws[49 + f0] * x0.y + Ws[50 + f0] * x0.z + Ws[51 + f0] * x0.w
             + Ws[64 + f0] * x1a + Ws[65 + f0] * x1b + Ws[66 + f0] * x1c + Ws[67 + f0] * x1d
             + Ws[80 + f0] * x2a + Ws[81 + f0] * x2b + Ws[82 + f0] * x2c + Ws[83 + f0] * x2d;
    t0 += __shfl_xor(t0, 2, 4); t0 += __shfl_xor(t0, 1, 4);
    t1 += __shfl_xor(t1, 2, 4); t1 += __shfl_xor(t1, 1, 4);
    if (h == 0) {
        out[(size_t)n * 2 + 0] = fmaxf(t0, 0.f);
        out[(size_t)n * 2 + 1] = fmaxf(t1, 0.f);
    }
}

extern "C" void kernel_launch(void* const* d_in, const int* in_sizes, int n_in,
                              void* d_out, int out_size, void* d_ws, size_t ws_size,
                              hipStream_t stream) {
    const float* X0  = (const float*)d_in[0];
    const float* W   = (const float*)d_in[1];
    const int*   src = (const int*)d_in[2];
    const int*   dst = (const int*)d_in[3];
    const float* lm  = (const float*)d_in[4];
    float* out = (float*)d_out;

    // Workspace (~37 MB of 256MiB):
    // hxg[NBLK*HXW] | csort[NE] | es[NBUK*LCAP] | P[NN]
    // | Y0[(NN+1)*F bf16] | Y1[(NN+1)*F bf16]
    int*   hxg   = (int*)d_ws;
    int*   csort = hxg + (size_t)NBLK * HXW;
    int*   es    = csort + NE;
    unsigned int* P = (unsigned int*)(es + (size_t)NBUK * LCAP);
    unsigned short* Y0 = (unsigned short*)(P + NN);
    unsigned short* Y1 = Y0 + (size_t)(NN + 1) * F;

    k_lsort<<<NBLK, 512, 0, stream>>>(src, dst, hxg, csort);
    k_sort <<<NBUK, 512, 0, stream>>>(csort, hxg, X0, es, P, Y0, Y1);
    k_prop1<<<NBUK * 2, 256, 0, stream>>>(P, es, Y0, X0, lm, Y1);
    k_prop2<<<NBUK * 2, 256, 0, stream>>>(P, es, Y1, X0, lm, W, out);
}